// Round 3
// baseline (508.335 us; speedup 1.0000x reference)
//
#include <hip/hip_runtime.h>
#include <hip/hip_bf16.h>

// SDPA fwd, full attn materialization. B=2,H=16,S=2048,D=64, fp32 I/O, bf16 MFMA.
// R3: phase 1 (denominators) is now BARRIER-FREE: K B-frags gathered directly
// from global (L2/L3-warm) + in-reg cvt; no LDS in phase 1. LDS down to 48KB
// (K16+V16+P16) -> 3 blocks/CU, launch_bounds(256,3). Phase 2 unchanged from
// R2 (staged K/V, reg-prefetch, B-frag-order V, coalesced float4 attn stores).

typedef __bf16 bf16;
typedef __attribute__((ext_vector_type(8))) __bf16 bf16x8;
typedef __attribute__((ext_vector_type(4))) __bf16 bf16x4;
typedef __attribute__((ext_vector_type(4))) float f32x4;

#define NBH  32
#define SEQ  2048
#define DH   64
#define QB   64
#define KV   128
#define NT   32
#define SCL  0.125f
#define NEGV -10000.0f

__device__ __forceinline__ int swzK(int row, int colB) { return row * 128 + (colB ^ ((row & 7) << 4)); }
__device__ __forceinline__ int swzP(int row, int colB) { return row * 256 + (colB ^ ((row & 7) << 4)); }

__global__ __launch_bounds__(256, 3)
void sdpa_kernel(const float* __restrict__ qg, const float* __restrict__ kg,
                 const float* __restrict__ vg, const float* __restrict__ mg,
                 float* __restrict__ og, float* __restrict__ ag)
{
    __shared__ __align__(16) unsigned char smem[49152]; // K 16K | V 16K | P 4x4K
    unsigned char* smK = smem;
    unsigned char* smV = smem + 16384;

    const int tid  = threadIdx.x;
    const int w    = tid >> 6;
    const int lane = tid & 63;
    const int g    = lane >> 4;
    const int c    = lane & 15;

    const int bh = blockIdx.x & 31;
    const int pi = blockIdx.x >> 5;     // pair index 0..15
    const int bb = bh >> 4;

    const float* qp = qg + (size_t)bh * SEQ * DH;
    const float* kp = kg + (size_t)bh * SEQ * DH;
    const float* vp = vg + (size_t)bh * SEQ * DH;
    const float* mp = mg + (size_t)bb * SEQ;
    float* op = og + (size_t)bh * SEQ * DH;
    float* ap = ag + (size_t)bh * (size_t)SEQ * SEQ;

    unsigned char* smP = smem + 32768 + w * 4096;  // wave-private [16][128] bf16

    // staging thread->element maps (phase 2)
    const int krow = tid >> 4, kd4 = tid & 15;
    const int vkg  = (tid >> 4) * 8, vd4 = tid & 15;
    const int vks2 = vkg >> 5, vhi = (vkg >> 3) & 3;

    for (int sp = 0; sp < 2; ++sp) {
        const int qt  = sp ? pi : (NT - 1 - pi);   // heavy stripe first
        const int nt2 = (qt + 2) >> 1;             // #128-wide K tiles
        const int qr0 = qt * QB;
        const int wr0 = qr0 + w * 16;

        // ---- zero-fill attn cols [nt2*KV, SEQ) (exact: softmax underflows to 0) ----
        {
            int fillc = nt2 * KV;
            if (fillc < SEQ) {
                int row = tid >> 2;
                float* rp = ap + (size_t)(qr0 + row) * SEQ + fillc;
                int n4 = (SEQ - fillc) >> 2;
                float4 z = make_float4(0.f, 0.f, 0.f, 0.f);
                for (int j = tid & 3; j < n4; j += 4) ((float4*)rp)[j] = z;
            }
        }

        // ---- Q A-frags (row = lane&15, k = g*8+j within 32-chunk) ----
        bf16x8 qf[2];
        {
            const float* src = qp + (size_t)(wr0 + c) * DH;
            #pragma unroll
            for (int ks = 0; ks < 2; ++ks) {
                f32x4 x0 = *(const f32x4*)(src + ks * 32 + g * 8);
                f32x4 x1 = *(const f32x4*)(src + ks * 32 + g * 8 + 4);
                bf16x8 t;
                t[0]=(bf16)x0[0]; t[1]=(bf16)x0[1]; t[2]=(bf16)x0[2]; t[3]=(bf16)x0[3];
                t[4]=(bf16)x1[0]; t[5]=(bf16)x1[1]; t[6]=(bf16)x1[2]; t[7]=(bf16)x1[3];
                qf[ks] = t;
            }
        }

        float lsum[4] = {0.f, 0.f, 0.f, 0.f};

        // ========= phase 1: denominators — barrier-free, K direct from global =========
        for (int t = 0; t < nt2; ++t) {
            const int k0 = t * KV;
            const bool diag = (k0 + KV > qr0);
            #pragma unroll
            for (int kf = 0; kf < 8; ++kf) {
                const int kcol = k0 + kf * 16 + c;
                const float madd = (1.0f - mp[kcol]) * NEGV;
                const float* kr = kp + (size_t)kcol * DH;
                f32x4 acc = {0.f, 0.f, 0.f, 0.f};
                #pragma unroll
                for (int ks = 0; ks < 2; ++ks) {
                    f32x4 x0 = *(const f32x4*)(kr + ks * 32 + g * 8);
                    f32x4 x1 = *(const f32x4*)(kr + ks * 32 + g * 8 + 4);
                    bf16x8 kb;
                    kb[0]=(bf16)x0[0]; kb[1]=(bf16)x0[1]; kb[2]=(bf16)x0[2]; kb[3]=(bf16)x0[3];
                    kb[4]=(bf16)x1[0]; kb[5]=(bf16)x1[1]; kb[6]=(bf16)x1[2]; kb[7]=(bf16)x1[3];
                    acc = __builtin_amdgcn_mfma_f32_16x16x32_bf16(qf[ks], kb, acc, 0, 0, 0);
                }
                #pragma unroll
                for (int r = 0; r < 4; ++r) {
                    float s = acc[r] * SCL + madd;
                    if (diag && kcol > wr0 + g * 4 + r) s += NEGV;
                    lsum[r] += __expf(s);
                }
            }
        }

        float linv[4];
        #pragma unroll
        for (int r = 0; r < 4; ++r) {
            float s = lsum[r];
            s += __shfl_xor(s, 1, 64); s += __shfl_xor(s, 2, 64);
            s += __shfl_xor(s, 4, 64); s += __shfl_xor(s, 8, 64);
            linv[r] = 1.0f / s;
        }

        // ================= phase 2: P writes + PV =================
        f32x4 oacc[4];
        { f32x4 z = {0.f, 0.f, 0.f, 0.f}; for (int d = 0; d < 4; ++d) oacc[d] = z; }

        f32x4 krg[8], vrg[8];
        #pragma unroll
        for (int i = 0; i < 8; ++i) {
            krg[i] = *(const f32x4*)(kp + (size_t)(krow + i * 16) * DH + kd4 * 4);
            vrg[i] = *(const f32x4*)(vp + (size_t)(vkg + i) * DH + vd4 * 4);
        }
        __syncthreads();   // prior-phase LDS readers done
        #pragma unroll
        for (int i = 0; i < 8; ++i) {
            bf16x4 tt; tt[0]=(bf16)krg[i][0]; tt[1]=(bf16)krg[i][1]; tt[2]=(bf16)krg[i][2]; tt[3]=(bf16)krg[i][3];
            *(bf16x4*)(smK + swzK(krow + i * 16, kd4 * 8)) = tt;
        }
        #pragma unroll
        for (int e = 0; e < 4; ++e) {   // V in B-frag order, conflict-free b128
            int d = vd4 * 4 + e, df = d >> 4, cc = d & 15;
            int b = (vks2 * 4 + df) * 64 + vhi * 16 + cc;
            b ^= df ^ (((cc >> 3) & 1) << 2);
            bf16x8 tv;
            #pragma unroll
            for (int i = 0; i < 8; ++i) tv[i] = (bf16)vrg[i][e];
            *(bf16x8*)(smV + b * 16) = tv;
        }
        __syncthreads();

        for (int t = 0; t < nt2; ++t) {
            const int k0 = t * KV;
            if (t + 1 < nt2) {
                #pragma unroll
                for (int i = 0; i < 8; ++i) {
                    krg[i] = *(const f32x4*)(kp + (size_t)(k0 + KV + krow + i * 16) * DH + kd4 * 4);
                    vrg[i] = *(const f32x4*)(vp + (size_t)(k0 + KV + vkg + i) * DH + vd4 * 4);
                }
            }
            f32x4 sacc[8];
            #pragma unroll
            for (int kf = 0; kf < 8; ++kf) {
                f32x4 acc = {0.f, 0.f, 0.f, 0.f};
                #pragma unroll
                for (int ks = 0; ks < 2; ++ks) {
                    bf16x8 kb = *(const bf16x8*)(smK + swzK(kf * 16 + c, ks * 64 + g * 16));
                    acc = __builtin_amdgcn_mfma_f32_16x16x32_bf16(qf[ks], kb, acc, 0, 0, 0);
                }
                sacc[kf] = acc;
            }
            const bool diag = (k0 + KV > qr0);
            #pragma unroll
            for (int kf = 0; kf < 8; ++kf) {
                const int kcol = k0 + kf * 16 + c;
                const float madd = (1.0f - mp[kcol]) * NEGV;
                #pragma unroll
                for (int r = 0; r < 4; ++r) {
                    float s = sacc[kf][r] * SCL + madd;
                    if (diag && kcol > wr0 + g * 4 + r) s += NEGV;
                    float p = __expf(s) * linv[r];
                    *(bf16*)(smP + swzP(g * 4 + r, kf * 32 + c * 2)) = (bf16)p;
                }
            }
            // PV: A = P (LDS A-frag order), B = V (LDS B-frag order)
            #pragma unroll
            for (int ks2 = 0; ks2 < 4; ++ks2) {
                bf16x8 pf = *(const bf16x8*)(smP + swzP(c, ks2 * 64 + g * 16));
                #pragma unroll
                for (int df = 0; df < 4; ++df) {
                    int b = (ks2 * 4 + df) * 64 + lane;
                    b ^= df ^ (((lane >> 3) & 1) << 2);
                    bf16x8 vf = *(const bf16x8*)(smV + b * 16);
                    oacc[df] = __builtin_amdgcn_mfma_f32_16x16x32_bf16(pf, vf, oacc[df], 0, 0, 0);
                }
            }
            // attn tile store: smP readback -> coalesced float4 (bf16-rounded)
            {
                int row = lane >> 2;
                float* dst = ap + (size_t)(wr0 + row) * SEQ + k0 + (lane & 3) * 4;
                #pragma unroll
                for (int st = 0; st < 8; ++st) {
                    bf16x4 pb = *(const bf16x4*)(smP + swzP(row, (lane & 3) * 8 + st * 32));
                    float4 o;
                    o.x = (float)pb[0]; o.y = (float)pb[1]; o.z = (float)pb[2]; o.w = (float)pb[3];
                    *(float4*)(dst + st * 16) = o;
                }
            }
            if (t + 1 < nt2) {
                __syncthreads();
                #pragma unroll
                for (int i = 0; i < 8; ++i) {
                    bf16x4 tt; tt[0]=(bf16)krg[i][0]; tt[1]=(bf16)krg[i][1]; tt[2]=(bf16)krg[i][2]; tt[3]=(bf16)krg[i][3];
                    *(bf16x4*)(smK + swzK(krow + i * 16, kd4 * 8)) = tt;
                }
                #pragma unroll
                for (int e = 0; e < 4; ++e) {
                    int d = vd4 * 4 + e, df = d >> 4, cc = d & 15;
                    int b = (vks2 * 4 + df) * 64 + vhi * 16 + cc;
                    b ^= df ^ (((cc >> 3) & 1) << 2);
                    bf16x8 tv;
                    #pragma unroll
                    for (int i = 0; i < 8; ++i) tv[i] = (bf16)vrg[i][e];
                    *(bf16x8*)(smV + b * 16) = tv;
                }
                __syncthreads();
            }
        }

        // ---- O store ----
        #pragma unroll
        for (int df = 0; df < 4; ++df)
            #pragma unroll
            for (int r = 0; r < 4; ++r)
                op[(size_t)(wr0 + g * 4 + r) * DH + df * 16 + c] = oacc[df][r];
    }
}

extern "C" void kernel_launch(void* const* d_in, const int* in_sizes, int n_in,
                              void* d_out, int out_size, void* d_ws, size_t ws_size,
                              hipStream_t stream)
{
    const float* q = (const float*)d_in[0];
    const float* k = (const float*)d_in[1];
    const float* v = (const float*)d_in[2];
    const float* m = (const float*)d_in[3];
    float* outO = (float*)d_out;
    float* outA = (float*)d_out + (size_t)NBH * SEQ * DH;
    dim3 grid(NBH * 16);
    dim3 block(256);
    hipLaunchKernelGGL(sdpa_kernel, grid, block, 0, stream, q, k, v, m, outO, outA);
}

// Round 4
// 423.583 us; speedup vs baseline: 1.2001x; 1.2001x over previous
//
#include <hip/hip_runtime.h>
#include <hip/hip_bf16.h>

// SDPA fwd, full attn materialization. B=2,H=16,S=2048,D=64, fp32 I/O, bf16 MFMA.
// R4: swapped-operand layout everywhere — mfma(K,Q) makes each lane own ONE
// q-row (c=lane&15) with 4 consecutive k-cols per acc reg. Scalar lsum/linv,
// multiplicative binary mask (float4 loads), attn stored straight from regs,
// P->PV via 1.25KB/wave LDS bounce (b64 writes + b128 reads, 2-way max).
// K staged via LDS (coalesced) — R3's global K gather was a 2x regression
// (374MB overfetch). LDS 37KB -> 4 blocks/CU.

typedef __bf16 bf16;
typedef __attribute__((ext_vector_type(8))) __bf16 bf16x8;
typedef __attribute__((ext_vector_type(4))) __bf16 bf16x4;
typedef __attribute__((ext_vector_type(4))) float f32x4;

#define NBH  32
#define SEQ  2048
#define DH   64
#define QB   64
#define KV   128
#define NT   32
#define SCL  0.125f

__device__ __forceinline__ int swzK(int row, int colB) { return row * 128 + (colB ^ ((row & 7) << 4)); }

__global__ __launch_bounds__(256, 4)
void sdpa_kernel(const float* __restrict__ qg, const float* __restrict__ kg,
                 const float* __restrict__ vg, const float* __restrict__ mg,
                 float* __restrict__ og, float* __restrict__ ag)
{
    // K 16K | V 16K | P-bounce 4x1280B  = 37.9KB
    __shared__ __align__(16) unsigned char smem[37888];
    unsigned char* smK = smem;
    unsigned char* smV = smem + 16384;

    const int tid  = threadIdx.x;
    const int w    = tid >> 6;
    const int lane = tid & 63;
    const int g    = lane >> 4;
    const int c    = lane & 15;

    const int bh = blockIdx.x & 31;
    const int pi = blockIdx.x >> 5;     // pair index 0..15
    const int bb = bh >> 4;

    const float* qp = qg + (size_t)bh * SEQ * DH;
    const float* kp = kg + (size_t)bh * SEQ * DH;
    const float* vp = vg + (size_t)bh * SEQ * DH;
    const float* mp = mg + (size_t)bb * SEQ;
    float* op = og + (size_t)bh * SEQ * DH;
    float* ap = ag + (size_t)bh * (size_t)SEQ * SEQ;

    unsigned char* smP = smem + 32768 + w * 1280;  // per-wave [16 rows][80B]

    // staging thread->element maps
    const int krow = tid >> 4, kd4 = tid & 15;
    const int vkg  = (tid >> 4) * 8, vd4 = tid & 15;
    const int vks2 = vkg >> 5, vhi = (vkg >> 3) & 3;

    for (int sp = 0; sp < 2; ++sp) {
        const int qt  = sp ? pi : (NT - 1 - pi);   // heavy stripe first
        const int nt2 = (qt + 2) >> 1;             // #128-wide K tiles
        const int qr0 = qt * QB;
        const int wr0 = qr0 + w * 16;
        const int qrow = wr0 + c;                  // this lane's q-row

        // ---- zero-fill attn cols [nt2*KV, SEQ) (exact: softmax underflows) ----
        {
            int fillc = nt2 * KV;
            if (fillc < SEQ) {
                int row = tid >> 2;
                float* rp = ap + (size_t)(qr0 + row) * SEQ + fillc;
                int n4 = (SEQ - fillc) >> 2;
                float4 z = make_float4(0.f, 0.f, 0.f, 0.f);
                for (int j = tid & 3; j < n4; j += 4) ((float4*)rp)[j] = z;
            }
        }

        // ---- Q B-frags (col = c -> q-row, k = g*8+j within 32-chunk) ----
        bf16x8 qf[2];
        {
            const float* src = qp + (size_t)qrow * DH;
            #pragma unroll
            for (int ks = 0; ks < 2; ++ks) {
                f32x4 x0 = *(const f32x4*)(src + ks * 32 + g * 8);
                f32x4 x1 = *(const f32x4*)(src + ks * 32 + g * 8 + 4);
                bf16x8 t;
                t[0]=(bf16)x0[0]; t[1]=(bf16)x0[1]; t[2]=(bf16)x0[2]; t[3]=(bf16)x0[3];
                t[4]=(bf16)x1[0]; t[5]=(bf16)x1[1]; t[6]=(bf16)x1[2]; t[7]=(bf16)x1[3];
                qf[ks] = t;
            }
        }

        float lsum = 0.f;
        f32x4 krg[8], vrg[8];

        // ================= phase 1: denominators =================
        #pragma unroll
        for (int i = 0; i < 8; ++i)
            krg[i] = *(const f32x4*)(kp + (size_t)(krow + i * 16) * DH + kd4 * 4);
        __syncthreads();
        #pragma unroll
        for (int i = 0; i < 8; ++i) {
            bf16x4 t; t[0]=(bf16)krg[i][0]; t[1]=(bf16)krg[i][1]; t[2]=(bf16)krg[i][2]; t[3]=(bf16)krg[i][3];
            *(bf16x4*)(smK + swzK(krow + i * 16, kd4 * 8)) = t;
        }
        __syncthreads();

        for (int t = 0; t < nt2; ++t) {
            const int k0 = t * KV;
            if (t + 1 < nt2) {
                #pragma unroll
                for (int i = 0; i < 8; ++i)
                    krg[i] = *(const f32x4*)(kp + (size_t)(k0 + KV + krow + i * 16) * DH + kd4 * 4);
            }
            const bool diag = (k0 + KV > qr0);
            #pragma unroll
            for (int kf = 0; kf < 8; ++kf) {
                f32x4 acc = {0.f, 0.f, 0.f, 0.f};
                #pragma unroll
                for (int ks = 0; ks < 2; ++ks) {
                    bf16x8 kb = *(const bf16x8*)(smK + swzK(kf * 16 + c, ks * 64 + g * 16));
                    acc = __builtin_amdgcn_mfma_f32_16x16x32_bf16(kb, qf[ks], acc, 0, 0, 0);
                }
                f32x4 m4 = *(const f32x4*)(mp + k0 + kf * 16 + g * 4);
                #pragma unroll
                for (int r = 0; r < 4; ++r) {
                    float e = __expf(acc[r] * SCL) * m4[r];
                    if (diag && (k0 + kf * 16 + g * 4 + r) > qrow) e = 0.f;
                    lsum += e;
                }
            }
            if (t + 1 < nt2) {
                __syncthreads();
                #pragma unroll
                for (int i = 0; i < 8; ++i) {
                    bf16x4 tt; tt[0]=(bf16)krg[i][0]; tt[1]=(bf16)krg[i][1]; tt[2]=(bf16)krg[i][2]; tt[3]=(bf16)krg[i][3];
                    *(bf16x4*)(smK + swzK(krow + i * 16, kd4 * 8)) = tt;
                }
                __syncthreads();
            }
        }

        lsum += __shfl_xor(lsum, 16, 64);
        lsum += __shfl_xor(lsum, 32, 64);
        const float linv = 1.0f / lsum;

        // ================= phase 2: P stores + PV =================
        f32x4 oacc[4];
        { f32x4 z = {0.f, 0.f, 0.f, 0.f}; for (int d = 0; d < 4; ++d) oacc[d] = z; }

        #pragma unroll
        for (int i = 0; i < 8; ++i) {
            krg[i] = *(const f32x4*)(kp + (size_t)(krow + i * 16) * DH + kd4 * 4);
            vrg[i] = *(const f32x4*)(vp + (size_t)(vkg + i) * DH + vd4 * 4);
        }
        __syncthreads();
        #pragma unroll
        for (int i = 0; i < 8; ++i) {
            bf16x4 tt; tt[0]=(bf16)krg[i][0]; tt[1]=(bf16)krg[i][1]; tt[2]=(bf16)krg[i][2]; tt[3]=(bf16)krg[i][3];
            *(bf16x4*)(smK + swzK(krow + i * 16, kd4 * 8)) = tt;
        }
        #pragma unroll
        for (int e = 0; e < 4; ++e) {   // V in frag order, conflict-free b128
            int d = vd4 * 4 + e, df = d >> 4, cc = d & 15;
            int b = (vks2 * 4 + df) * 64 + vhi * 16 + cc;
            b ^= df ^ (((cc >> 3) & 1) << 2);
            bf16x8 tv;
            #pragma unroll
            for (int i = 0; i < 8; ++i) tv[i] = (bf16)vrg[i][e];
            *(bf16x8*)(smV + b * 16) = tv;
        }
        __syncthreads();

        for (int t = 0; t < nt2; ++t) {
            const int k0 = t * KV;
            if (t + 1 < nt2) {
                #pragma unroll
                for (int i = 0; i < 8; ++i) {
                    krg[i] = *(const f32x4*)(kp + (size_t)(k0 + KV + krow + i * 16) * DH + kd4 * 4);
                    vrg[i] = *(const f32x4*)(vp + (size_t)(k0 + KV + vkg + i) * DH + vd4 * 4);
                }
            }
            const bool diag = (k0 + KV > qr0);
            f32x4 p[8];
            #pragma unroll
            for (int kf = 0; kf < 8; ++kf) {
                f32x4 acc = {0.f, 0.f, 0.f, 0.f};
                #pragma unroll
                for (int ks = 0; ks < 2; ++ks) {
                    bf16x8 kb = *(const bf16x8*)(smK + swzK(kf * 16 + c, ks * 64 + g * 16));
                    acc = __builtin_amdgcn_mfma_f32_16x16x32_bf16(kb, qf[ks], acc, 0, 0, 0);
                }
                f32x4 m4 = *(const f32x4*)(mp + k0 + kf * 16 + g * 4);
                f32x4 pv;
                #pragma unroll
                for (int r = 0; r < 4; ++r) {
                    float e = __expf(acc[r] * SCL) * m4[r] * linv;
                    if (diag && (k0 + kf * 16 + g * 4 + r) > qrow) e = 0.f;
                    pv[r] = e;
                }
                p[kf] = pv;
                *(f32x4*)(ap + (size_t)qrow * SEQ + k0 + kf * 16 + g * 4) = pv;
            }
            // PV: bounce P^T through per-wave LDS chunk, then mfma(V, P)
            #pragma unroll
            for (int ks2 = 0; ks2 < 4; ++ks2) {
                #pragma unroll
                for (int b = 0; b < 2; ++b) {
                    f32x4 pv = p[ks2 * 2 + b];
                    bf16x4 tb; tb[0]=(bf16)pv[0]; tb[1]=(bf16)pv[1]; tb[2]=(bf16)pv[2]; tb[3]=(bf16)pv[3];
                    *(bf16x4*)(smP + c * 80 + b * 32 + g * 8) = tb;
                }
                bf16x8 pf = *(const bf16x8*)(smP + c * 80 + g * 16);
                #pragma unroll
                for (int df = 0; df < 4; ++df) {
                    int b = (ks2 * 4 + df) * 64 + lane;
                    b ^= df ^ (((lane >> 3) & 1) << 2);
                    bf16x8 vf = *(const bf16x8*)(smV + b * 16);
                    oacc[df] = __builtin_amdgcn_mfma_f32_16x16x32_bf16(vf, pf, oacc[df], 0, 0, 0);
                }
            }
            if (t + 1 < nt2) {
                __syncthreads();
                #pragma unroll
                for (int i = 0; i < 8; ++i) {
                    bf16x4 tt; tt[0]=(bf16)krg[i][0]; tt[1]=(bf16)krg[i][1]; tt[2]=(bf16)krg[i][2]; tt[3]=(bf16)krg[i][3];
                    *(bf16x4*)(smK + swzK(krow + i * 16, kd4 * 8)) = tt;
                }
                #pragma unroll
                for (int e = 0; e < 4; ++e) {
                    int d = vd4 * 4 + e, df = d >> 4, cc = d & 15;
                    int b = (vks2 * 4 + df) * 64 + vhi * 16 + cc;
                    b ^= df ^ (((cc >> 3) & 1) << 2);
                    bf16x8 tv;
                    #pragma unroll
                    for (int i = 0; i < 8; ++i) tv[i] = (bf16)vrg[i][e];
                    *(bf16x8*)(smV + b * 16) = tv;
                }
                __syncthreads();
            }
        }

        // ---- O store: row = q (lane c), 4 contiguous d per df ----
        #pragma unroll
        for (int df = 0; df < 4; ++df) {
            float4 o;
            o.x = oacc[df][0]; o.y = oacc[df][1]; o.z = oacc[df][2]; o.w = oacc[df][3];
            *(float4*)(op + (size_t)qrow * DH + df * 16 + g * 4) = o;
        }
    }
}

extern "C" void kernel_launch(void* const* d_in, const int* in_sizes, int n_in,
                              void* d_out, int out_size, void* d_ws, size_t ws_size,
                              hipStream_t stream)
{
    const float* q = (const float*)d_in[0];
    const float* k = (const float*)d_in[1];
    const float* v = (const float*)d_in[2];
    const float* m = (const float*)d_in[3];
    float* outO = (float*)d_out;
    float* outA = (float*)d_out + (size_t)NBH * SEQ * DH;
    dim3 grid(NBH * 16);
    dim3 block(256);
    hipLaunchKernelGGL(sdpa_kernel, grid, block, 0, stream, q, k, v, m, outO, outA);
}

// Round 5
// 319.448 us; speedup vs baseline: 1.5913x; 1.3260x over previous
//
#include <hip/hip_runtime.h>
#include <hip/hip_bf16.h>

// SDPA fwd, full attn materialization. B=2,H=16,S=2048,D=64, fp32 I/O, bf16 MFMA.
// R5: swapped-QK^T (scalar softmax) kept from R4, but ALL global stores are
// lane-contiguous: P goes to a per-wave 4KB swizzled LDS tile; attn store =
// coalesced readback (2 rows x 512B per instruction); PV B-frags read from the
// same tile; O bounced through LDS too (4 rows x 256B per instruction).
// R4's scattered 16B stores caused 246MB write + 345MB fetch RMW amplification.
// LDS 48KB (K16|V16|P16) -> 3 blocks/CU.

typedef __bf16 bf16;
typedef __attribute__((ext_vector_type(8))) __bf16 bf16x8;
typedef __attribute__((ext_vector_type(4))) __bf16 bf16x4;
typedef __attribute__((ext_vector_type(4))) float f32x4;

#define NBH  32
#define SEQ  2048
#define DH   64
#define QB   64
#define KV   128
#define NT   32
#define SCL  0.125f

__device__ __forceinline__ int swzK(int row, int colB) { return row * 128 + (colB ^ ((row & 7) << 4)); }
__device__ __forceinline__ int swzP(int row, int colB) { return row * 256 + (colB ^ ((row & 7) << 5)); }

__global__ __launch_bounds__(256, 3)
void sdpa_kernel(const float* __restrict__ qg, const float* __restrict__ kg,
                 const float* __restrict__ vg, const float* __restrict__ mg,
                 float* __restrict__ og, float* __restrict__ ag)
{
    // K 16K | V 16K | P 4x4K (per-wave [16 rows][256B], swizzled)
    __shared__ __align__(16) unsigned char smem[49152];
    unsigned char* smK = smem;
    unsigned char* smV = smem + 16384;

    const int tid  = threadIdx.x;
    const int w    = tid >> 6;
    const int lane = tid & 63;
    const int g    = lane >> 4;
    const int c    = lane & 15;

    const int bh = blockIdx.x & 31;
    const int pi = blockIdx.x >> 5;     // pair index 0..15
    const int bb = bh >> 4;

    const float* qp = qg + (size_t)bh * SEQ * DH;
    const float* kp = kg + (size_t)bh * SEQ * DH;
    const float* vp = vg + (size_t)bh * SEQ * DH;
    const float* mp = mg + (size_t)bb * SEQ;
    float* op = og + (size_t)bh * SEQ * DH;
    float* ap = ag + (size_t)bh * (size_t)SEQ * SEQ;

    unsigned char* smP = smem + 32768 + w * 4096;

    // staging thread->element maps
    const int krow = tid >> 4, kd4 = tid & 15;
    const int vkg  = (tid >> 4) * 8, vd4 = tid & 15;
    const int vks2 = vkg >> 5, vhi = (vkg >> 3) & 3;

    for (int sp = 0; sp < 2; ++sp) {
        const int qt  = sp ? pi : (NT - 1 - pi);   // heavy stripe first
        const int nt2 = (qt + 2) >> 1;             // #128-wide K tiles
        const int qr0 = qt * QB;
        const int wr0 = qr0 + w * 16;
        const int qrow = wr0 + c;                  // this lane's q-row

        // ---- zero-fill attn cols [nt2*KV, SEQ) (exact: softmax underflows) ----
        {
            int fillc = nt2 * KV;
            if (fillc < SEQ) {
                int row = tid >> 2;
                float* rp = ap + (size_t)(qr0 + row) * SEQ + fillc;
                int n4 = (SEQ - fillc) >> 2;
                float4 z = make_float4(0.f, 0.f, 0.f, 0.f);
                for (int j = tid & 3; j < n4; j += 4) ((float4*)rp)[j] = z;
            }
        }

        // ---- Q B-frags (col = c -> q-row, k = g*8+j within 32-chunk) ----
        bf16x8 qf[2];
        {
            const float* src = qp + (size_t)qrow * DH;
            #pragma unroll
            for (int ks = 0; ks < 2; ++ks) {
                f32x4 x0 = *(const f32x4*)(src + ks * 32 + g * 8);
                f32x4 x1 = *(const f32x4*)(src + ks * 32 + g * 8 + 4);
                bf16x8 t;
                t[0]=(bf16)x0[0]; t[1]=(bf16)x0[1]; t[2]=(bf16)x0[2]; t[3]=(bf16)x0[3];
                t[4]=(bf16)x1[0]; t[5]=(bf16)x1[1]; t[6]=(bf16)x1[2]; t[7]=(bf16)x1[3];
                qf[ks] = t;
            }
        }

        float lsum = 0.f;
        f32x4 krg[8], vrg[8];

        // ================= phase 1: denominators =================
        #pragma unroll
        for (int i = 0; i < 8; ++i)
            krg[i] = *(const f32x4*)(kp + (size_t)(krow + i * 16) * DH + kd4 * 4);
        __syncthreads();
        #pragma unroll
        for (int i = 0; i < 8; ++i) {
            bf16x4 t; t[0]=(bf16)krg[i][0]; t[1]=(bf16)krg[i][1]; t[2]=(bf16)krg[i][2]; t[3]=(bf16)krg[i][3];
            *(bf16x4*)(smK + swzK(krow + i * 16, kd4 * 8)) = t;
        }
        __syncthreads();

        for (int t = 0; t < nt2; ++t) {
            const int k0 = t * KV;
            if (t + 1 < nt2) {
                #pragma unroll
                for (int i = 0; i < 8; ++i)
                    krg[i] = *(const f32x4*)(kp + (size_t)(k0 + KV + krow + i * 16) * DH + kd4 * 4);
            }
            const bool diag = (k0 + KV > qr0);
            #pragma unroll
            for (int kf = 0; kf < 8; ++kf) {
                f32x4 acc = {0.f, 0.f, 0.f, 0.f};
                #pragma unroll
                for (int ks = 0; ks < 2; ++ks) {
                    bf16x8 kb = *(const bf16x8*)(smK + swzK(kf * 16 + c, ks * 64 + g * 16));
                    acc = __builtin_amdgcn_mfma_f32_16x16x32_bf16(kb, qf[ks], acc, 0, 0, 0);
                }
                f32x4 m4 = *(const f32x4*)(mp + k0 + kf * 16 + g * 4);
                #pragma unroll
                for (int r = 0; r < 4; ++r) {
                    float e = __expf(acc[r] * SCL) * m4[r];
                    if (diag && (k0 + kf * 16 + g * 4 + r) > qrow) e = 0.f;
                    lsum += e;
                }
            }
            if (t + 1 < nt2) {
                __syncthreads();
                #pragma unroll
                for (int i = 0; i < 8; ++i) {
                    bf16x4 tt; tt[0]=(bf16)krg[i][0]; tt[1]=(bf16)krg[i][1]; tt[2]=(bf16)krg[i][2]; tt[3]=(bf16)krg[i][3];
                    *(bf16x4*)(smK + swzK(krow + i * 16, kd4 * 8)) = tt;
                }
                __syncthreads();
            }
        }

        lsum += __shfl_xor(lsum, 16, 64);
        lsum += __shfl_xor(lsum, 32, 64);
        const float linv = 1.0f / lsum;

        // ================= phase 2: P -> LDS -> (attn store, PV) =================
        f32x4 oacc[4];
        { f32x4 z = {0.f, 0.f, 0.f, 0.f}; for (int d = 0; d < 4; ++d) oacc[d] = z; }

        #pragma unroll
        for (int i = 0; i < 8; ++i) {
            krg[i] = *(const f32x4*)(kp + (size_t)(krow + i * 16) * DH + kd4 * 4);
            vrg[i] = *(const f32x4*)(vp + (size_t)(vkg + i) * DH + vd4 * 4);
        }
        __syncthreads();
        #pragma unroll
        for (int i = 0; i < 8; ++i) {
            bf16x4 tt; tt[0]=(bf16)krg[i][0]; tt[1]=(bf16)krg[i][1]; tt[2]=(bf16)krg[i][2]; tt[3]=(bf16)krg[i][3];
            *(bf16x4*)(smK + swzK(krow + i * 16, kd4 * 8)) = tt;
        }
        #pragma unroll
        for (int e = 0; e < 4; ++e) {   // V in frag order, conflict-free b128
            int d = vd4 * 4 + e, df = d >> 4, cc = d & 15;
            int b = (vks2 * 4 + df) * 64 + vhi * 16 + cc;
            b ^= df ^ (((cc >> 3) & 1) << 2);
            bf16x8 tv;
            #pragma unroll
            for (int i = 0; i < 8; ++i) tv[i] = (bf16)vrg[i][e];
            *(bf16x8*)(smV + b * 16) = tv;
        }
        __syncthreads();

        for (int t = 0; t < nt2; ++t) {
            const int k0 = t * KV;
            if (t + 1 < nt2) {
                #pragma unroll
                for (int i = 0; i < 8; ++i) {
                    krg[i] = *(const f32x4*)(kp + (size_t)(k0 + KV + krow + i * 16) * DH + kd4 * 4);
                    vrg[i] = *(const f32x4*)(vp + (size_t)(k0 + KV + vkg + i) * DH + vd4 * 4);
                }
            }
            const bool diag = (k0 + KV > qr0);
            // scores -> P (bf16) into per-wave LDS tile
            #pragma unroll
            for (int kf = 0; kf < 8; ++kf) {
                f32x4 acc = {0.f, 0.f, 0.f, 0.f};
                #pragma unroll
                for (int ks = 0; ks < 2; ++ks) {
                    bf16x8 kb = *(const bf16x8*)(smK + swzK(kf * 16 + c, ks * 64 + g * 16));
                    acc = __builtin_amdgcn_mfma_f32_16x16x32_bf16(kb, qf[ks], acc, 0, 0, 0);
                }
                f32x4 m4 = *(const f32x4*)(mp + k0 + kf * 16 + g * 4);
                bf16x4 tb;
                #pragma unroll
                for (int r = 0; r < 4; ++r) {
                    float e = __expf(acc[r] * SCL) * m4[r] * linv;
                    if (diag && (k0 + kf * 16 + g * 4 + r) > qrow) e = 0.f;
                    tb[r] = (bf16)e;
                }
                *(bf16x4*)(smP + swzP(c, kf * 32 + g * 8)) = tb;
            }
            // attn store: coalesced readback, 2 rows x 512B contiguous per instr
            {
                const int rr = lane >> 5, cc = lane & 31;
                #pragma unroll
                for (int i = 0; i < 8; ++i) {
                    int row = i * 2 + rr;
                    bf16x4 pb = *(const bf16x4*)(smP + swzP(row, cc * 8));
                    float4 o;
                    o.x = (float)pb[0]; o.y = (float)pb[1]; o.z = (float)pb[2]; o.w = (float)pb[3];
                    *(float4*)(ap + (size_t)(wr0 + row) * SEQ + k0 + cc * 4) = o;
                }
            }
            // PV: A = V (frag order), B = P^T (from smP)
            #pragma unroll
            for (int ks2 = 0; ks2 < 4; ++ks2) {
                bf16x8 pf = *(const bf16x8*)(smP + swzP(c, ks2 * 64 + g * 16));
                #pragma unroll
                for (int df = 0; df < 4; ++df) {
                    int b = (ks2 * 4 + df) * 64 + lane;
                    b ^= df ^ (((lane >> 3) & 1) << 2);
                    bf16x8 vf = *(const bf16x8*)(smV + b * 16);
                    oacc[df] = __builtin_amdgcn_mfma_f32_16x16x32_bf16(vf, pf, oacc[df], 0, 0, 0);
                }
            }
            if (t + 1 < nt2) {
                __syncthreads();
                #pragma unroll
                for (int i = 0; i < 8; ++i) {
                    bf16x4 tt; tt[0]=(bf16)krg[i][0]; tt[1]=(bf16)krg[i][1]; tt[2]=(bf16)krg[i][2]; tt[3]=(bf16)krg[i][3];
                    *(bf16x4*)(smK + swzK(krow + i * 16, kd4 * 8)) = tt;
                }
                #pragma unroll
                for (int e = 0; e < 4; ++e) {
                    int d = vd4 * 4 + e, df = d >> 4, cc = d & 15;
                    int b = (vks2 * 4 + df) * 64 + vhi * 16 + cc;
                    b ^= df ^ (((cc >> 3) & 1) << 2);
                    bf16x8 tv;
                    #pragma unroll
                    for (int i = 0; i < 8; ++i) tv[i] = (bf16)vrg[i][e];
                    *(bf16x8*)(smV + b * 16) = tv;
                }
                __syncthreads();
            }
        }

        // ---- O store via LDS bounce: 4 rows x 256B contiguous per instr ----
        #pragma unroll
        for (int df = 0; df < 4; ++df)
            *(f32x4*)(smP + swzP(c, df * 64 + g * 16)) = oacc[df];
        {
            const int rr = lane >> 4, cc16 = lane & 15;
            #pragma unroll
            for (int i = 0; i < 4; ++i) {
                int row = i * 4 + rr;
                f32x4 ov = *(const f32x4*)(smP + swzP(row, cc16 * 16));
                float4 o; o.x = ov[0]; o.y = ov[1]; o.z = ov[2]; o.w = ov[3];
                *(float4*)(op + (size_t)(wr0 + row) * DH + cc16 * 4) = o;
            }
        }
    }
}

extern "C" void kernel_launch(void* const* d_in, const int* in_sizes, int n_in,
                              void* d_out, int out_size, void* d_ws, size_t ws_size,
                              hipStream_t stream)
{
    const float* q = (const float*)d_in[0];
    const float* k = (const float*)d_in[1];
    const float* v = (const float*)d_in[2];
    const float* m = (const float*)d_in[3];
    float* outO = (float*)d_out;
    float* outA = (float*)d_out + (size_t)NBH * SEQ * DH;
    dim3 grid(NBH * 16);
    dim3 block(256);
    hipLaunchKernelGGL(sdpa_kernel, grid, block, 0, stream, q, k, v, m, outO, outA);
}

// Round 6
// 178.310 us; speedup vs baseline: 2.8508x; 1.7915x over previous
//
#include <hip/hip_runtime.h>
#include <hip/hip_bf16.h>

// SDPA fwd, full attn materialization. B=2,H=16,S=2048,D=64, fp32 I/O, bf16 MFMA.
// R6 = R5 inner loop (swapped QK^T, scalar softmax, lane-contiguous LDS-bounced
// stores) with: (1) 1024 single-stripe blocks, heavy-first, for even CU packing;
// (2) nontemporal attn/fill/O stores so the 512MB write stream doesn't evict
// K/V from L2/L3 (R5: FETCH 179MB vs 56MB ideal); (3) 48KB LDS, 3 blocks/CU.

typedef __bf16 bf16;
typedef __attribute__((ext_vector_type(8))) __bf16 bf16x8;
typedef __attribute__((ext_vector_type(4))) __bf16 bf16x4;
typedef __attribute__((ext_vector_type(4))) float f32x4;

#define NBH  32
#define SEQ  2048
#define DH   64
#define QB   64
#define KV   128
#define NT   32
#define SCL  0.125f

__device__ __forceinline__ int swzK(int row, int colB) { return row * 128 + (colB ^ ((row & 7) << 4)); }
__device__ __forceinline__ int swzP(int row, int colB) { return row * 256 + (colB ^ ((row & 7) << 5)); }

__device__ __forceinline__ void nt_store4(float* p, float x, float y, float z, float w) {
    f32x4 v = {x, y, z, w};
    __builtin_nontemporal_store(v, (f32x4*)p);
}

__global__ __launch_bounds__(256, 3)
void sdpa_kernel(const float* __restrict__ qg, const float* __restrict__ kg,
                 const float* __restrict__ vg, const float* __restrict__ mg,
                 float* __restrict__ og, float* __restrict__ ag)
{
    // K 16K | V 16K | P 4x4K (per-wave [16 rows][256B], swizzled)
    __shared__ __align__(16) unsigned char smem[49152];
    unsigned char* smK = smem;
    unsigned char* smV = smem + 16384;

    const int tid  = threadIdx.x;
    const int w    = tid >> 6;
    const int lane = tid & 63;
    const int g    = lane >> 4;
    const int c    = lane & 15;

    const int bh = blockIdx.x & 31;
    const int qt = (NT - 1) - (blockIdx.x >> 5);   // heavy stripes dispatched first
    const int bb = bh >> 4;

    const float* qp = qg + (size_t)bh * SEQ * DH;
    const float* kp = kg + (size_t)bh * SEQ * DH;
    const float* vp = vg + (size_t)bh * SEQ * DH;
    const float* mp = mg + (size_t)bb * SEQ;
    float* op = og + (size_t)bh * SEQ * DH;
    float* ap = ag + (size_t)bh * (size_t)SEQ * SEQ;

    unsigned char* smP = smem + 32768 + w * 4096;

    // staging thread->element maps
    const int krow = tid >> 4, kd4 = tid & 15;
    const int vkg  = (tid >> 4) * 8, vd4 = tid & 15;
    const int vks2 = vkg >> 5, vhi = (vkg >> 3) & 3;

    const int nt2 = (qt + 2) >> 1;             // #128-wide K tiles
    const int qr0 = qt * QB;
    const int wr0 = qr0 + w * 16;
    const int qrow = wr0 + c;                  // this lane's q-row

    // ---- zero-fill attn cols [nt2*KV, SEQ) (exact: softmax underflows) ----
    {
        int fillc = nt2 * KV;
        if (fillc < SEQ) {
            int row = tid >> 2;
            float* rp = ap + (size_t)(qr0 + row) * SEQ + fillc;
            int n4 = (SEQ - fillc) >> 2;
            for (int j = tid & 3; j < n4; j += 4)
                nt_store4(rp + j * 4, 0.f, 0.f, 0.f, 0.f);
        }
    }

    // ---- Q B-frags (col = c -> q-row, k = g*8+j within 32-chunk) ----
    bf16x8 qf[2];
    {
        const float* src = qp + (size_t)qrow * DH;
        #pragma unroll
        for (int ks = 0; ks < 2; ++ks) {
            f32x4 x0 = *(const f32x4*)(src + ks * 32 + g * 8);
            f32x4 x1 = *(const f32x4*)(src + ks * 32 + g * 8 + 4);
            bf16x8 t;
            t[0]=(bf16)x0[0]; t[1]=(bf16)x0[1]; t[2]=(bf16)x0[2]; t[3]=(bf16)x0[3];
            t[4]=(bf16)x1[0]; t[5]=(bf16)x1[1]; t[6]=(bf16)x1[2]; t[7]=(bf16)x1[3];
            qf[ks] = t;
        }
    }

    float lsum = 0.f;
    f32x4 krg[8], vrg[8];

    // ================= phase 1: denominators =================
    #pragma unroll
    for (int i = 0; i < 8; ++i)
        krg[i] = *(const f32x4*)(kp + (size_t)(krow + i * 16) * DH + kd4 * 4);
    #pragma unroll
    for (int i = 0; i < 8; ++i) {
        bf16x4 t; t[0]=(bf16)krg[i][0]; t[1]=(bf16)krg[i][1]; t[2]=(bf16)krg[i][2]; t[3]=(bf16)krg[i][3];
        *(bf16x4*)(smK + swzK(krow + i * 16, kd4 * 8)) = t;
    }
    __syncthreads();

    for (int t = 0; t < nt2; ++t) {
        const int k0 = t * KV;
        if (t + 1 < nt2) {
            #pragma unroll
            for (int i = 0; i < 8; ++i)
                krg[i] = *(const f32x4*)(kp + (size_t)(k0 + KV + krow + i * 16) * DH + kd4 * 4);
        }
        const bool diag = (k0 + KV > qr0);
        #pragma unroll
        for (int kf = 0; kf < 8; ++kf) {
            f32x4 acc = {0.f, 0.f, 0.f, 0.f};
            #pragma unroll
            for (int ks = 0; ks < 2; ++ks) {
                bf16x8 kb = *(const bf16x8*)(smK + swzK(kf * 16 + c, ks * 64 + g * 16));
                acc = __builtin_amdgcn_mfma_f32_16x16x32_bf16(kb, qf[ks], acc, 0, 0, 0);
            }
            f32x4 m4 = *(const f32x4*)(mp + k0 + kf * 16 + g * 4);
            #pragma unroll
            for (int r = 0; r < 4; ++r) {
                float e = __expf(acc[r] * SCL) * m4[r];
                if (diag && (k0 + kf * 16 + g * 4 + r) > qrow) e = 0.f;
                lsum += e;
            }
        }
        if (t + 1 < nt2) {
            __syncthreads();
            #pragma unroll
            for (int i = 0; i < 8; ++i) {
                bf16x4 tt; tt[0]=(bf16)krg[i][0]; tt[1]=(bf16)krg[i][1]; tt[2]=(bf16)krg[i][2]; tt[3]=(bf16)krg[i][3];
                *(bf16x4*)(smK + swzK(krow + i * 16, kd4 * 8)) = tt;
            }
            __syncthreads();
        }
    }

    lsum += __shfl_xor(lsum, 16, 64);
    lsum += __shfl_xor(lsum, 32, 64);
    const float linv = 1.0f / lsum;

    // ================= phase 2: P -> LDS -> (attn store, PV) =================
    f32x4 oacc[4];
    { f32x4 z = {0.f, 0.f, 0.f, 0.f}; for (int d = 0; d < 4; ++d) oacc[d] = z; }

    #pragma unroll
    for (int i = 0; i < 8; ++i) {
        krg[i] = *(const f32x4*)(kp + (size_t)(krow + i * 16) * DH + kd4 * 4);
        vrg[i] = *(const f32x4*)(vp + (size_t)(vkg + i) * DH + vd4 * 4);
    }
    __syncthreads();
    #pragma unroll
    for (int i = 0; i < 8; ++i) {
        bf16x4 tt; tt[0]=(bf16)krg[i][0]; tt[1]=(bf16)krg[i][1]; tt[2]=(bf16)krg[i][2]; tt[3]=(bf16)krg[i][3];
        *(bf16x4*)(smK + swzK(krow + i * 16, kd4 * 8)) = tt;
    }
    #pragma unroll
    for (int e = 0; e < 4; ++e) {   // V in frag order, conflict-free b128
        int d = vd4 * 4 + e, df = d >> 4, cc = d & 15;
        int b = (vks2 * 4 + df) * 64 + vhi * 16 + cc;
        b ^= df ^ (((cc >> 3) & 1) << 2);
        bf16x8 tv;
        #pragma unroll
        for (int i = 0; i < 8; ++i) tv[i] = (bf16)vrg[i][e];
        *(bf16x8*)(smV + b * 16) = tv;
    }
    __syncthreads();

    for (int t = 0; t < nt2; ++t) {
        const int k0 = t * KV;
        if (t + 1 < nt2) {
            #pragma unroll
            for (int i = 0; i < 8; ++i) {
                krg[i] = *(const f32x4*)(kp + (size_t)(k0 + KV + krow + i * 16) * DH + kd4 * 4);
                vrg[i] = *(const f32x4*)(vp + (size_t)(k0 + KV + vkg + i) * DH + vd4 * 4);
            }
        }
        const bool diag = (k0 + KV > qr0);
        // scores -> P (bf16) into per-wave LDS tile
        #pragma unroll
        for (int kf = 0; kf < 8; ++kf) {
            f32x4 acc = {0.f, 0.f, 0.f, 0.f};
            #pragma unroll
            for (int ks = 0; ks < 2; ++ks) {
                bf16x8 kb = *(const bf16x8*)(smK + swzK(kf * 16 + c, ks * 64 + g * 16));
                acc = __builtin_amdgcn_mfma_f32_16x16x32_bf16(kb, qf[ks], acc, 0, 0, 0);
            }
            f32x4 m4 = *(const f32x4*)(mp + k0 + kf * 16 + g * 4);
            bf16x4 tb;
            #pragma unroll
            for (int r = 0; r < 4; ++r) {
                float e = __expf(acc[r] * SCL) * m4[r] * linv;
                if (diag && (k0 + kf * 16 + g * 4 + r) > qrow) e = 0.f;
                tb[r] = (bf16)e;
            }
            *(bf16x4*)(smP + swzP(c, kf * 32 + g * 8)) = tb;
        }
        // attn store: coalesced readback, 2 rows x 512B contiguous per instr
        {
            const int rr = lane >> 5, cc = lane & 31;
            #pragma unroll
            for (int i = 0; i < 8; ++i) {
                int row = i * 2 + rr;
                bf16x4 pb = *(const bf16x4*)(smP + swzP(row, cc * 8));
                nt_store4(ap + (size_t)(wr0 + row) * SEQ + k0 + cc * 4,
                          (float)pb[0], (float)pb[1], (float)pb[2], (float)pb[3]);
            }
        }
        // PV: A = V (frag order), B = P^T (from smP)
        #pragma unroll
        for (int ks2 = 0; ks2 < 4; ++ks2) {
            bf16x8 pf = *(const bf16x8*)(smP + swzP(c, ks2 * 64 + g * 16));
            #pragma unroll
            for (int df = 0; df < 4; ++df) {
                int b = (ks2 * 4 + df) * 64 + lane;
                b ^= df ^ (((lane >> 3) & 1) << 2);
                bf16x8 vf = *(const bf16x8*)(smV + b * 16);
                oacc[df] = __builtin_amdgcn_mfma_f32_16x16x32_bf16(vf, pf, oacc[df], 0, 0, 0);
            }
        }
        if (t + 1 < nt2) {
            __syncthreads();
            #pragma unroll
            for (int i = 0; i < 8; ++i) {
                bf16x4 tt; tt[0]=(bf16)krg[i][0]; tt[1]=(bf16)krg[i][1]; tt[2]=(bf16)krg[i][2]; tt[3]=(bf16)krg[i][3];
                *(bf16x4*)(smK + swzK(krow + i * 16, kd4 * 8)) = tt;
            }
            #pragma unroll
            for (int e = 0; e < 4; ++e) {
                int d = vd4 * 4 + e, df = d >> 4, cc = d & 15;
                int b = (vks2 * 4 + df) * 64 + vhi * 16 + cc;
                b ^= df ^ (((cc >> 3) & 1) << 2);
                bf16x8 tv;
                #pragma unroll
                for (int i = 0; i < 8; ++i) tv[i] = (bf16)vrg[i][e];
                *(bf16x8*)(smV + b * 16) = tv;
            }
            __syncthreads();
        }
    }

    // ---- O store via LDS bounce: 4 rows x 256B contiguous per instr ----
    __syncthreads();
    #pragma unroll
    for (int df = 0; df < 4; ++df)
        *(f32x4*)(smP + swzP(c, df * 64 + g * 16)) = oacc[df];
    {
        const int rr = lane >> 4, cc16 = lane & 15;
        #pragma unroll
        for (int i = 0; i < 4; ++i) {
            int row = i * 4 + rr;
            f32x4 ov = *(const f32x4*)(smP + swzP(row, cc16 * 16));
            nt_store4(op + (size_t)(wr0 + row) * DH + cc16 * 4, ov[0], ov[1], ov[2], ov[3]);
        }
    }
}

extern "C" void kernel_launch(void* const* d_in, const int* in_sizes, int n_in,
                              void* d_out, int out_size, void* d_ws, size_t ws_size,
                              hipStream_t stream)
{
    const float* q = (const float*)d_in[0];
    const float* k = (const float*)d_in[1];
    const float* v = (const float*)d_in[2];
    const float* m = (const float*)d_in[3];
    float* outO = (float*)d_out;
    float* outA = (float*)d_out + (size_t)NBH * SEQ * DH;
    dim3 grid(NBH * NT);
    dim3 block(256);
    hipLaunchKernelGGL(sdpa_kernel, grid, block, 0, stream, q, k, v, m, outO, outA);
}

// Round 8
// 145.462 us; speedup vs baseline: 3.4946x; 1.2258x over previous
//
#include <hip/hip_runtime.h>
#include <hip/hip_bf16.h>

// SDPA fwd, full attn materialization. B=2,H=16,S=2048,D=64, fp32 I/O, bf16 MFMA.
// R8 = R7 with compile fix: __exp2f/__log2f -> __builtin_amdgcn_exp2f /
// __builtin_amdgcn_logf (v_exp_f32 = 2^x, v_log_f32 = log2 on gfx950).
// R7 changes under test: (1) raw barriers WITHOUT vmcnt drain; (2) phase-1 K
// double-buffered -> 1 barrier/tile; (3) Q pre-scaled by SCL*log2e, linv
// folded additively (exp2 path).

typedef __bf16 bf16;
typedef __attribute__((ext_vector_type(8))) __bf16 bf16x8;
typedef __attribute__((ext_vector_type(4))) __bf16 bf16x4;
typedef __attribute__((ext_vector_type(4))) float f32x4;

#define NBH  32
#define SEQ  2048
#define DH   64
#define QB   64
#define KV   128
#define NT   32
#define QSCL 0.18033688f   // 0.125 * log2(e)

__device__ __forceinline__ int swzK(int row, int colB) { return row * 128 + (colB ^ ((row & 7) << 4)); }
__device__ __forceinline__ int swzP(int row, int colB) { return row * 256 + (colB ^ ((row & 7) << 5)); }

__device__ __forceinline__ void nt_store4(float* p, float x, float y, float z, float w) {
    f32x4 v = {x, y, z, w};
    __builtin_nontemporal_store(v, (f32x4*)p);
}

// Block barrier that does NOT drain vmcnt: LDS ordering only. ds_reads are
// consumed (register deps) before any wave reaches the barrier; ds_writes are
// covered by lgkmcnt(0). Global NT stores / prefetch loads stay outstanding.
__device__ __forceinline__ void block_sync_lds() {
    __builtin_amdgcn_sched_barrier(0);
    asm volatile("s_waitcnt lgkmcnt(0)" ::: "memory");
    __builtin_amdgcn_s_barrier();
    __builtin_amdgcn_sched_barrier(0);
}

__global__ __launch_bounds__(256, 3)
void sdpa_kernel(const float* __restrict__ qg, const float* __restrict__ kg,
                 const float* __restrict__ vg, const float* __restrict__ mg,
                 float* __restrict__ og, float* __restrict__ ag)
{
    // phase 1: K dbuf in [0,16K)+[16K,32K) | phase 2: K 16K | V 16K | P 4x4K
    __shared__ __align__(16) unsigned char smem[49152];
    unsigned char* smK = smem;
    unsigned char* smV = smem + 16384;

    const int tid  = threadIdx.x;
    const int w    = tid >> 6;
    const int lane = tid & 63;
    const int g    = lane >> 4;
    const int c    = lane & 15;

    const int bh = blockIdx.x & 31;
    const int qt = (NT - 1) - (blockIdx.x >> 5);   // heavy stripes first
    const int bb = bh >> 4;

    const float* qp = qg + (size_t)bh * SEQ * DH;
    const float* kp = kg + (size_t)bh * SEQ * DH;
    const float* vp = vg + (size_t)bh * SEQ * DH;
    const float* mp = mg + (size_t)bb * SEQ;
    float* op = og + (size_t)bh * SEQ * DH;
    float* ap = ag + (size_t)bh * (size_t)SEQ * SEQ;

    unsigned char* smP = smem + 32768 + w * 4096;

    const int krow = tid >> 4, kd4 = tid & 15;
    const int vkg  = (tid >> 4) * 8, vd4 = tid & 15;
    const int vks2 = vkg >> 5, vhi = (vkg >> 3) & 3;

    const int nt2 = (qt + 2) >> 1;             // #128-wide K tiles
    const int qr0 = qt * QB;
    const int wr0 = qr0 + w * 16;
    const int qrow = wr0 + c;                  // this lane's q-row

    // ---- zero-fill attn cols [nt2*KV, SEQ): 16 lanes/row -> 256B runs ----
    {
        int fillc = nt2 * KV;
        if (fillc < SEQ) {
            int row = tid >> 4, j0 = tid & 15;
            int n4 = (SEQ - fillc) >> 2;
            #pragma unroll
            for (int rr = 0; rr < 4; ++rr) {
                float* rp = ap + (size_t)(qr0 + rr * 16 + row) * SEQ + fillc;
                for (int j = j0; j < n4; j += 16)
                    nt_store4(rp + j * 4, 0.f, 0.f, 0.f, 0.f);
            }
        }
    }

    // ---- Q B-frags, pre-scaled by SCL*log2e ----
    bf16x8 qf[2];
    {
        const float* src = qp + (size_t)qrow * DH;
        #pragma unroll
        for (int ks = 0; ks < 2; ++ks) {
            f32x4 x0 = *(const f32x4*)(src + ks * 32 + g * 8);
            f32x4 x1 = *(const f32x4*)(src + ks * 32 + g * 8 + 4);
            bf16x8 t;
            t[0]=(bf16)(x0[0]*QSCL); t[1]=(bf16)(x0[1]*QSCL); t[2]=(bf16)(x0[2]*QSCL); t[3]=(bf16)(x0[3]*QSCL);
            t[4]=(bf16)(x1[0]*QSCL); t[5]=(bf16)(x1[1]*QSCL); t[6]=(bf16)(x1[2]*QSCL); t[7]=(bf16)(x1[3]*QSCL);
            qf[ks] = t;
        }
    }

    float lsum = 0.f;
    f32x4 krg[8], vrg[8];

    // ========= phase 1: denominators, K double-buffered, 1 barrier/tile =========
    #pragma unroll
    for (int i = 0; i < 8; ++i)
        krg[i] = *(const f32x4*)(kp + (size_t)(krow + i * 16) * DH + kd4 * 4);
    #pragma unroll
    for (int i = 0; i < 8; ++i) {
        bf16x4 t4; t4[0]=(bf16)krg[i][0]; t4[1]=(bf16)krg[i][1]; t4[2]=(bf16)krg[i][2]; t4[3]=(bf16)krg[i][3];
        *(bf16x4*)(smem + swzK(krow + i * 16, kd4 * 8)) = t4;
    }
    block_sync_lds();

    int cur = 0;
    for (int t = 0; t < nt2; ++t) {
        const int k0 = t * KV;
        if (t + 1 < nt2) {
            #pragma unroll
            for (int i = 0; i < 8; ++i)
                krg[i] = *(const f32x4*)(kp + (size_t)(k0 + KV + krow + i * 16) * DH + kd4 * 4);
        }
        const unsigned char* kb_base = smem + cur * 16384;
        const bool diag = (k0 + KV > qr0);
        #pragma unroll
        for (int kf = 0; kf < 8; ++kf) {
            f32x4 acc = {0.f, 0.f, 0.f, 0.f};
            #pragma unroll
            for (int ks = 0; ks < 2; ++ks) {
                bf16x8 kb = *(const bf16x8*)(kb_base + swzK(kf * 16 + c, ks * 64 + g * 16));
                acc = __builtin_amdgcn_mfma_f32_16x16x32_bf16(kb, qf[ks], acc, 0, 0, 0);
            }
            f32x4 m4 = *(const f32x4*)(mp + k0 + kf * 16 + g * 4);
            #pragma unroll
            for (int r = 0; r < 4; ++r) {
                float e = __builtin_amdgcn_exp2f(acc[r]) * m4[r];
                if (diag && (k0 + kf * 16 + g * 4 + r) > qrow) e = 0.f;
                lsum += e;
            }
        }
        if (t + 1 < nt2) {
            unsigned char* wb = smem + (cur ^ 1) * 16384;
            #pragma unroll
            for (int i = 0; i < 8; ++i) {
                bf16x4 t4; t4[0]=(bf16)krg[i][0]; t4[1]=(bf16)krg[i][1]; t4[2]=(bf16)krg[i][2]; t4[3]=(bf16)krg[i][3];
                *(bf16x4*)(wb + swzK(krow + i * 16, kd4 * 8)) = t4;
            }
            block_sync_lds();
            cur ^= 1;
        }
    }

    lsum += __shfl_xor(lsum, 16, 64);
    lsum += __shfl_xor(lsum, 32, 64);
    const float llinv = -__builtin_amdgcn_logf(lsum);   // -log2(lsum)

    // ================= phase 2: P -> LDS -> (attn store, PV) =================
    f32x4 oacc[4];
    { f32x4 z = {0.f, 0.f, 0.f, 0.f}; for (int d = 0; d < 4; ++d) oacc[d] = z; }

    #pragma unroll
    for (int i = 0; i < 8; ++i) {
        krg[i] = *(const f32x4*)(kp + (size_t)(krow + i * 16) * DH + kd4 * 4);
        vrg[i] = *(const f32x4*)(vp + (size_t)(vkg + i) * DH + vd4 * 4);
    }
    block_sync_lds();   // phase-1 readers done before overwriting smK/smV
    #pragma unroll
    for (int i = 0; i < 8; ++i) {
        bf16x4 t4; t4[0]=(bf16)krg[i][0]; t4[1]=(bf16)krg[i][1]; t4[2]=(bf16)krg[i][2]; t4[3]=(bf16)krg[i][3];
        *(bf16x4*)(smK + swzK(krow + i * 16, kd4 * 8)) = t4;
    }
    #pragma unroll
    for (int e = 0; e < 4; ++e) {   // V in frag order, conflict-free b128
        int d = vd4 * 4 + e, df = d >> 4, cc = d & 15;
        int b = (vks2 * 4 + df) * 64 + vhi * 16 + cc;
        b ^= df ^ (((cc >> 3) & 1) << 2);
        bf16x8 tv;
        #pragma unroll
        for (int i = 0; i < 8; ++i) tv[i] = (bf16)vrg[i][e];
        *(bf16x8*)(smV + b * 16) = tv;
    }
    block_sync_lds();

    for (int t = 0; t < nt2; ++t) {
        const int k0 = t * KV;
        if (t + 1 < nt2) {
            #pragma unroll
            for (int i = 0; i < 8; ++i) {
                krg[i] = *(const f32x4*)(kp + (size_t)(k0 + KV + krow + i * 16) * DH + kd4 * 4);
                vrg[i] = *(const f32x4*)(vp + (size_t)(k0 + KV + vkg + i) * DH + vd4 * 4);
            }
        }
        const bool diag = (k0 + KV > qr0);
        // scores -> P (bf16) into per-wave LDS tile
        #pragma unroll
        for (int kf = 0; kf < 8; ++kf) {
            f32x4 acc = {0.f, 0.f, 0.f, 0.f};
            #pragma unroll
            for (int ks = 0; ks < 2; ++ks) {
                bf16x8 kb = *(const bf16x8*)(smK + swzK(kf * 16 + c, ks * 64 + g * 16));
                acc = __builtin_amdgcn_mfma_f32_16x16x32_bf16(kb, qf[ks], acc, 0, 0, 0);
            }
            f32x4 m4 = *(const f32x4*)(mp + k0 + kf * 16 + g * 4);
            bf16x4 tb;
            #pragma unroll
            for (int r = 0; r < 4; ++r) {
                float e = __builtin_amdgcn_exp2f(acc[r] + llinv) * m4[r];
                if (diag && (k0 + kf * 16 + g * 4 + r) > qrow) e = 0.f;
                tb[r] = (bf16)e;
            }
            *(bf16x4*)(smP + swzP(c, kf * 32 + g * 8)) = tb;
        }
        // attn store: coalesced readback, 2 rows x 512B contiguous per instr
        {
            const int rr = lane >> 5, cc = lane & 31;
            #pragma unroll
            for (int i = 0; i < 8; ++i) {
                int row = i * 2 + rr;
                bf16x4 pb = *(const bf16x4*)(smP + swzP(row, cc * 8));
                nt_store4(ap + (size_t)(wr0 + row) * SEQ + k0 + cc * 4,
                          (float)pb[0], (float)pb[1], (float)pb[2], (float)pb[3]);
            }
        }
        // PV: A = V (frag order), B = P^T (from smP)
        #pragma unroll
        for (int ks2 = 0; ks2 < 4; ++ks2) {
            bf16x8 pf = *(const bf16x8*)(smP + swzP(c, ks2 * 64 + g * 16));
            #pragma unroll
            for (int df = 0; df < 4; ++df) {
                int b = (ks2 * 4 + df) * 64 + lane;
                b ^= df ^ (((lane >> 3) & 1) << 2);
                bf16x8 vf = *(const bf16x8*)(smV + b * 16);
                oacc[df] = __builtin_amdgcn_mfma_f32_16x16x32_bf16(vf, pf, oacc[df], 0, 0, 0);
            }
        }
        if (t + 1 < nt2) {
            block_sync_lds();
            #pragma unroll
            for (int i = 0; i < 8; ++i) {
                bf16x4 t4; t4[0]=(bf16)krg[i][0]; t4[1]=(bf16)krg[i][1]; t4[2]=(bf16)krg[i][2]; t4[3]=(bf16)krg[i][3];
                *(bf16x4*)(smK + swzK(krow + i * 16, kd4 * 8)) = t4;
            }
            #pragma unroll
            for (int e = 0; e < 4; ++e) {
                int d = vd4 * 4 + e, df = d >> 4, cc = d & 15;
                int b = (vks2 * 4 + df) * 64 + vhi * 16 + cc;
                b ^= df ^ (((cc >> 3) & 1) << 2);
                bf16x8 tv;
                #pragma unroll
                for (int i = 0; i < 8; ++i) tv[i] = (bf16)vrg[i][e];
                *(bf16x8*)(smV + b * 16) = tv;
            }
            block_sync_lds();
        }
    }

    // ---- O store via per-wave LDS bounce (same-wave DS ordering, no barrier) ----
    #pragma unroll
    for (int df = 0; df < 4; ++df)
        *(f32x4*)(smP + swzP(c, df * 64 + g * 16)) = oacc[df];
    {
        const int rr = lane >> 4, cc16 = lane & 15;
        #pragma unroll
        for (int i = 0; i < 4; ++i) {
            int row = i * 4 + rr;
            f32x4 ov = *(const f32x4*)(smP + swzP(row, cc16 * 16));
            nt_store4(op + (size_t)(wr0 + row) * DH + cc16 * 4, ov[0], ov[1], ov[2], ov[3]);
        }
    }
}

extern "C" void kernel_launch(void* const* d_in, const int* in_sizes, int n_in,
                              void* d_out, int out_size, void* d_ws, size_t ws_size,
                              hipStream_t stream)
{
    const float* q = (const float*)d_in[0];
    const float* k = (const float*)d_in[1];
    const float* v = (const float*)d_in[2];
    const float* m = (const float*)d_in[3];
    float* outO = (float*)d_out;
    float* outA = (float*)d_out + (size_t)NBH * SEQ * DH;
    dim3 grid(NBH * NT);
    dim3 block(256);
    hipLaunchKernelGGL(sdpa_kernel, grid, block, 0, stream, q, k, v, m, outO, outA);
}